// Round 1
// baseline (970.702 us; speedup 1.0000x reference)
//
#include <hip/hip_runtime.h>
#include <cstddef>

#define N_FFT 1024
#define HOP 256
#define NSTFT 513
#define N_MELS 80
#define BATCH 16
#define T_AUDIO 320000
#define NUM_FRAMES 1251
#define FPB 8
#define PAD 512

// One block: FPB frames of one batch. 256 threads.
// Phase 1: reflect-pad + window into LDS.
// Phase 2: DFT via provided cos/sin tables. Thread t owns bins k=t and k=t+256.
//          Bin 512 is skipped: mel filterbank weight for bin 512 (8000 Hz,
//          the exact endpoint of the last triangle) is 0, as is bin 0's.
// Phase 3: magnitude -> mel matmul -> transposed store.
__global__ __launch_bounds__(256) void melspec_kernel(
    const float* __restrict__ wav,     // B x T_AUDIO (channel dim squeezed)
    const float* __restrict__ window,  // 1024
    const float* __restrict__ fb,      // 513 x 80
    const float* __restrict__ cosT,    // 1024 x 513
    const float* __restrict__ sinT,    // 1024 x 513
    float* __restrict__ out)           // B x 80 x 1251
{
    __shared__ float sw[FPB][N_FFT];     // 32 KB
    __shared__ float smag[FPB][512];     // 16 KB

    const int t = threadIdx.x;
    const int b = blockIdx.y;
    const int frame0 = blockIdx.x * FPB;
    const int nf = min(FPB, NUM_FRAMES - frame0);

    const float* wb = wav + (size_t)b * T_AUDIO;

    // ---- Phase 1: load frames with reflect padding, apply window ----
    for (int idx = t; idx < FPB * N_FFT; idx += 256) {
        const int f = idx >> 10;
        const int n = idx & 1023;
        float v = 0.f;
        if (f < nf) {
            int j = (frame0 + f) * HOP + n - PAD;
            if (j < 0) j = -j;
            else if (j >= T_AUDIO) j = 2 * T_AUDIO - 2 - j;
            v = wb[j] * window[n];
        }
        sw[f][n] = v;
    }
    __syncthreads();

    // ---- Phase 2: DFT for bins k0 = t, k1 = t + 256 ----
    float racc0[FPB], iacc0[FPB], racc1[FPB], iacc1[FPB];
    #pragma unroll
    for (int f = 0; f < FPB; ++f) { racc0[f] = iacc0[f] = racc1[f] = iacc1[f] = 0.f; }

    const int k0 = t;
    const int k1 = t + 256;
    for (int n = 0; n < N_FFT; ++n) {
        const float c0 = cosT[n * NSTFT + k0];
        const float s0 = sinT[n * NSTFT + k0];
        const float c1 = cosT[n * NSTFT + k1];
        const float s1 = sinT[n * NSTFT + k1];
        #pragma unroll
        for (int f = 0; f < FPB; ++f) {
            const float w = sw[f][n];
            racc0[f] = fmaf(w, c0, racc0[f]);
            iacc0[f] = fmaf(w, s0, iacc0[f]);
            racc1[f] = fmaf(w, c1, racc1[f]);
            iacc1[f] = fmaf(w, s1, iacc1[f]);
        }
    }
    #pragma unroll
    for (int f = 0; f < FPB; ++f) {
        smag[f][k0] = sqrtf(racc0[f] * racc0[f] + iacc0[f] * iacc0[f]);
        smag[f][k1] = sqrtf(racc1[f] * racc1[f] + iacc1[f] * iacc1[f]);
    }
    __syncthreads();

    // ---- Phase 3: mel matmul + transposed store ----
    for (int task = t; task < N_MELS * FPB; task += 256) {
        const int m = task % N_MELS;
        const int f = task / N_MELS;
        if (f >= nf) continue;
        float acc = 0.f;
        for (int fbin = 0; fbin < 512; ++fbin) {
            acc = fmaf(smag[f][fbin], fb[fbin * N_MELS + m], acc);
        }
        out[((size_t)b * N_MELS + m) * NUM_FRAMES + (frame0 + f)] = acc;
    }
}

extern "C" void kernel_launch(void* const* d_in, const int* in_sizes, int n_in,
                              void* d_out, int out_size, void* d_ws, size_t ws_size,
                              hipStream_t stream) {
    const float* wav    = (const float*)d_in[0];  // 16 x 1 x 320000
    const float* window = (const float*)d_in[1];  // 1024
    const float* fb     = (const float*)d_in[2];  // 513 x 80
    const float* cosT   = (const float*)d_in[3];  // 1024 x 513
    const float* sinT   = (const float*)d_in[4];  // 1024 x 513
    float* out = (float*)d_out;                   // 16 x 80 x 1251

    dim3 grid((NUM_FRAMES + FPB - 1) / FPB, BATCH);
    melspec_kernel<<<grid, 256, 0, stream>>>(wav, window, fb, cosT, sinT, out);
}

// Round 2
// 155.978 us; speedup vs baseline: 6.2233x; 6.2233x over previous
//
#include <hip/hip_runtime.h>
#include <cstddef>

#define N_FFT 1024
#define HOP 256
#define NSTFT 513
#define N_MELS 80
#define BATCH 16
#define T_AUDIO 320000
#define NUM_FRAMES 1251
#define FPB 4
#define PAD 512

// Slaney mel-scale constants (double-derived, see reference):
// logstep = ln(6.4)/27 ; MEL_MAX = hz_to_mel(8000) = 15 + ln(8)/logstep
#define LOGSTEP 0.06875177742094913f
#define MEL_MAX 45.24564047f
#define DF 15.625f   // bin width = (SR/2)/(NSTFT-1)

__device__ __forceinline__ float mel_to_hz(float mel) {
    return (mel < 15.0f) ? (200.0f / 3.0f) * mel
                         : 1000.0f * expf(LOGSTEP * (mel - 15.0f));
}

// One block = 4 frames of one batch; wave w owns frame (blockIdx.x*4 + w).
// Phase 1: reflect-pad + Hann window -> LDS complex (im = 0).
// Phase 2: in-place radix-2 DIF FFT (10 stages). Twiddles W^j = exp(-2*pi*i*j/1024)
//          are exactly row n=1 of the supplied (cos,sin) tables.
// Phase 3: magnitude, un-bit-reversing the DIF output into natural bin order.
// Phase 4: sparse mel matmul - mel m only reads bins inside its triangle
//          [f_pts[m], f_pts[m+2]] (computed analytically, widened 2 bins);
//          weights still come from the supplied fb table. Bins 0 and 512
//          have exactly-zero weight and are excluded.
__global__ __launch_bounds__(256) void melspec_fft_kernel(
    const float* __restrict__ wav,     // B x T_AUDIO
    const float* __restrict__ window,  // 1024
    const float* __restrict__ fb,      // 513 x 80
    const float* __restrict__ cosT,    // 1024 x 513
    const float* __restrict__ sinT,    // 1024 x 513
    float* __restrict__ out)           // B x 80 x 1251
{
    __shared__ float2 sx[FPB][N_FFT];    // 32 KB
    __shared__ float2 stw[512];          // 4 KB twiddles
    __shared__ float  smag[FPB][NSTFT];  // 8.2 KB

    const int t = threadIdx.x;
    const int lane = t & 63;
    const int w = t >> 6;
    const int b = blockIdx.y;
    const int frame0 = blockIdx.x * FPB;
    const int frame = frame0 + w;
    const bool valid = frame < NUM_FRAMES;

    // twiddles from table row n=1: cosT[1][j] = cos(2*pi*j/N), sinT[1][j] = -sin(2*pi*j/N)
    for (int j = t; j < 512; j += 256) {
        stw[j] = make_float2(cosT[NSTFT + j], sinT[NSTFT + j]);
    }

    // ---- Phase 1: load + reflect pad + window ----
    const float* wb = wav + (size_t)b * T_AUDIO;
    if (valid) {
        const int base = frame * HOP - PAD;
        #pragma unroll
        for (int it = 0; it < 16; ++it) {
            const int n = lane + 64 * it;
            int j = base + n;
            if (j < 0) j = -j;
            else if (j >= T_AUDIO) j = 2 * T_AUDIO - 2 - j;
            sx[w][n] = make_float2(wb[j] * window[n], 0.0f);
        }
    } else {
        #pragma unroll
        for (int it = 0; it < 16; ++it) sx[w][lane + 64 * it] = make_float2(0.0f, 0.0f);
    }
    __syncthreads();

    // ---- Phase 2: radix-2 DIF FFT, 512 butterflies/stage, 8 per lane ----
    for (int stage = 0; stage < 10; ++stage) {
        const int half = 512 >> stage;
        const int hsh = 9 - stage;
        float2 va[8], vb[8];
        int i0a[8];
        #pragma unroll
        for (int it = 0; it < 8; ++it) {
            const int jj = lane + 64 * it;
            const int pos = jj & (half - 1);
            const int i0 = ((jj >> hsh) << (hsh + 1)) + pos;
            i0a[it] = i0;
            va[it] = sx[w][i0];
            vb[it] = sx[w][i0 + half];
        }
        #pragma unroll
        for (int it = 0; it < 8; ++it) {
            const int jj = lane + 64 * it;
            const int pos = jj & (half - 1);
            const float2 tw = stw[pos << stage];
            float2 s, d, o;
            s.x = va[it].x + vb[it].x; s.y = va[it].y + vb[it].y;
            d.x = va[it].x - vb[it].x; d.y = va[it].y - vb[it].y;
            o.x = d.x * tw.x - d.y * tw.y;
            o.y = d.x * tw.y + d.y * tw.x;
            sx[w][i0a[it]] = s;
            sx[w][i0a[it] + half] = o;
        }
        __syncthreads();
    }

    // ---- Phase 3: magnitude, bit-reversed gather -> natural order ----
    if (valid) {
        #pragma unroll
        for (int it = 0; it < 16; ++it) {
            const int p = lane + 64 * it;
            const int k = (int)(__brev((unsigned)p) >> 22);
            if (k < NSTFT) {
                const float2 v = sx[w][p];
                smag[w][k] = sqrtf(v.x * v.x + v.y * v.y);
            }
        }
    }
    __syncthreads();

    // ---- Phase 4: sparse mel matmul + transposed store ----
    for (int task = t; task < N_MELS * FPB; task += 256) {
        const int m = task >> 2;
        const int f = task & 3;
        if (frame0 + f >= NUM_FRAMES) continue;
        const float mlo = MEL_MAX * (float)m / 81.0f;
        const float mhi = MEL_MAX * (float)(m + 2) / 81.0f;
        const float flo = mel_to_hz(mlo);
        const float fhi = mel_to_hz(mhi);
        int klo = max(1, (int)(flo / DF) - 1);
        int khi = min(NSTFT - 2, (int)(fhi / DF) + 2);
        float acc = 0.0f;
        for (int k = klo; k <= khi; ++k) {
            acc = fmaf(smag[f][k], fb[k * N_MELS + m], acc);
        }
        out[((size_t)b * N_MELS + m) * NUM_FRAMES + frame0 + f] = acc;
    }
}

extern "C" void kernel_launch(void* const* d_in, const int* in_sizes, int n_in,
                              void* d_out, int out_size, void* d_ws, size_t ws_size,
                              hipStream_t stream) {
    const float* wav    = (const float*)d_in[0];  // 16 x 1 x 320000
    const float* window = (const float*)d_in[1];  // 1024
    const float* fb     = (const float*)d_in[2];  // 513 x 80
    const float* cosT   = (const float*)d_in[3];  // 1024 x 513
    const float* sinT   = (const float*)d_in[4];  // 1024 x 513
    float* out = (float*)d_out;                   // 16 x 80 x 1251

    dim3 grid((NUM_FRAMES + FPB - 1) / FPB, BATCH);
    melspec_fft_kernel<<<grid, 256, 0, stream>>>(wav, window, fb, cosT, sinT, out);
}

// Round 3
// 90.481 us; speedup vs baseline: 10.7282x; 1.7239x over previous
//
#include <hip/hip_runtime.h>
#include <cstddef>

#define HOP 256
#define NSTFT 513
#define N_MELS 80
#define T_AUDIO 320000
#define NUM_FRAMES 1251
#define NBATCH 16
#define TOTAL_FRAMES (NBATCH * NUM_FRAMES)   // 20016 (even)
#define NPAIRS (TOTAL_FRAMES / 2)            // 10008

// Slaney mel constants
#define LOGSTEP 0.06875177742094913f
#define MEL_MAX 45.24564047f
#define DF 15.625f

__device__ __forceinline__ float mel_to_hz(float mel) {
    return (mel < 15.0f) ? (200.0f / 3.0f) * mel
                         : 1000.0f * expf(LOGSTEP * (mel - 15.0f));
}

__device__ __forceinline__ int reflect_idx(int j) {
    j = (j < 0) ? -j : j;
    j = (j >= T_AUDIO) ? (2 * T_AUDIO - 2 - j) : j;
    return j;
}

// One wave = one PAIR of frames (real-packed complex FFT: re=frame g0, im=frame g1).
// Four-step 1024-pt FFT: n = n1*64 + lane, reg r holds n1.
//   A) 16-pt DIF FFT over registers (constant twiddles) -> reg r holds k1=brev4(r)
//   B) twiddle W_1024^{lane*k1} (preloaded from table row n=1 into VGPRs)
//   C) 64-pt DIF FFT across lanes via shfl_xor (6 stages) -> lane l holds k2=brev6(l)
// Z[k2*16+k1] then lives at (lane=brev6(k2), reg=brev4(k1)); the conjugate partner
// Z[1024-k] is at lane^63 (for k1!=0), fetched by one more shfl_xor. Magnitudes of
// both packed frames go to XOR-swizzled LDS slots (conflict-free), then the sparse
// mel matmul (each mel reads only its triangle) writes the transposed output.
// No __syncthreads anywhere: waves are fully independent.
__global__ __launch_bounds__(256) void melspec_sfft_kernel(
    const float* __restrict__ wav,     // 16 x 320000
    const float* __restrict__ window,  // 1024
    const float* __restrict__ fb,      // 513 x 80
    const float* __restrict__ cosT,    // 1024 x 513 (row 1 = cos(2*pi*j/1024))
    const float* __restrict__ sinT,    // 1024 x 513 (row 1 = -sin(2*pi*j/1024))
    float* __restrict__ out)           // 16 x 80 x 1251
{
    __shared__ float2 smag[4][NSTFT];  // per-wave magnitude buffer (A,B packed), ~16.4 KB

    const int lane = threadIdx.x & 63;
    const int w = threadIdx.x >> 6;
    const int pair = blockIdx.x * 4 + w;
    if (pair >= NPAIRS) return;

    const int g0 = 2 * pair;
    const unsigned b0 = (unsigned)g0 / NUM_FRAMES;
    const unsigned f0 = (unsigned)g0 - b0 * NUM_FRAMES;
    const unsigned b1 = (unsigned)(g0 + 1) / NUM_FRAMES;
    const unsigned f1 = (unsigned)(g0 + 1) - b1 * NUM_FRAMES;

    const int BREV4[16] = {0,8,4,12,2,10,6,14,1,9,5,13,3,11,7,15};
    const int SIG[16]   = {0,1,3,2,7,6,5,4,15,14,13,12,11,10,9,8};
    // W16^j = cos(2*pi*j/16) - i*sin(2*pi*j/16)
    const float W16R[8] = {1.0f, 0.92387953251128674f, 0.70710678118654752f, 0.38268343236508977f,
                           0.0f, -0.38268343236508977f, -0.70710678118654752f, -0.92387953251128674f};
    const float W16I[8] = {0.0f, -0.38268343236508977f, -0.70710678118654752f, -0.92387953251128674f,
                           -1.0f, -0.92387953251128674f, -0.70710678118654752f, -0.38268343236508977f};

    // ---- preload window + twiddles into VGPRs ----
    float win[16];
    #pragma unroll
    for (int r = 0; r < 16; ++r) win[r] = window[r * 64 + lane];

    const float* twc = cosT + NSTFT;  // row n=1
    const float* tws = sinT + NSTFT;

    float t1r[16], t1i[16];
    #pragma unroll
    for (int r = 0; r < 16; ++r) {
        const int j = lane * BREV4[r];          // 0..945
        if (j <= 512) { t1r[r] = twc[j];        t1i[r] = tws[j]; }
        else          { t1r[r] = twc[1024 - j]; t1i[r] = -tws[1024 - j]; }
    }
    float t64r[6], t64i[6];
    #pragma unroll
    for (int t = 0; t < 6; ++t) {
        const int half = 32 >> t;
        const int j = (lane & (half - 1)) << (t + 4);  // <= 496
        t64r[t] = twc[j];
        t64i[t] = tws[j];
    }

    // ---- load two frames (reflect pad) + window, packed as complex ----
    float zr[16], zi[16];
    {
        const float* wbA = wav + (size_t)b0 * T_AUDIO;
        const float* wbB = wav + (size_t)b1 * T_AUDIO;
        const int baseA = (int)f0 * HOP - 512;
        const int baseB = (int)f1 * HOP - 512;
        #pragma unroll
        for (int r = 0; r < 16; ++r) {
            const int n = r * 64 + lane;
            zr[r] = wbA[reflect_idx(baseA + n)] * win[r];
            zi[r] = wbB[reflect_idx(baseB + n)] * win[r];
        }
    }

    // ---- A) 16-pt DIF FFT over registers ----
    #define CBFLY(ar, ai, br, bi, wr, wi) { \
        const float _tr = (ar) - (br), _ti = (ai) - (bi); \
        (ar) += (br); (ai) += (bi); \
        (br) = _tr * (wr) - _ti * (wi); \
        (bi) = _tr * (wi) + _ti * (wr); }

    #pragma unroll
    for (int p = 0; p < 8; ++p) CBFLY(zr[p], zi[p], zr[p+8], zi[p+8], W16R[p], W16I[p]);
    #pragma unroll
    for (int g = 0; g < 16; g += 8)
        #pragma unroll
        for (int p = 0; p < 4; ++p) CBFLY(zr[g+p], zi[g+p], zr[g+p+4], zi[g+p+4], W16R[2*p], W16I[2*p]);
    #pragma unroll
    for (int g = 0; g < 16; g += 4)
        #pragma unroll
        for (int p = 0; p < 2; ++p) CBFLY(zr[g+p], zi[g+p], zr[g+p+2], zi[g+p+2], W16R[4*p], W16I[4*p]);
    #pragma unroll
    for (int g = 0; g < 16; g += 2) CBFLY(zr[g], zi[g], zr[g+1], zi[g+1], 1.0f, 0.0f);

    // ---- B) cross twiddle ----
    #pragma unroll
    for (int r = 0; r < 16; ++r) {
        const float xr = zr[r], xi = zi[r];
        zr[r] = xr * t1r[r] - xi * t1i[r];
        zi[r] = xr * t1i[r] + xi * t1r[r];
    }

    // ---- C) 64-pt DIF FFT across lanes ----
    #pragma unroll
    for (int t = 0; t < 6; ++t) {
        const int half = 32 >> t;
        const bool hi = (lane & half) != 0;
        #pragma unroll
        for (int r = 0; r < 16; ++r) {
            const float px = __shfl_xor(zr[r], half);
            const float py = __shfl_xor(zi[r], half);
            const float sx = zr[r] + px, sy = zi[r] + py;
            const float dx = px - zr[r], dy = py - zi[r];
            const float ox = dx * t64r[t] - dy * t64i[t];
            const float oy = dx * t64i[t] + dy * t64r[t];
            zr[r] = hi ? ox : sx;
            zi[r] = hi ? oy : sy;
        }
    }

    // ---- separation + magnitude + swizzled LDS store ----
    const int k2 = (int)(__brev((unsigned)lane) >> 26);
    const int lp0 = (int)(__brev((unsigned)((64 - k2) & 63)) >> 26);
    #pragma unroll
    for (int r = 0; r < 16; ++r) {
        float cx, cy;
        if (r == 0) { cx = __shfl(zr[0], lp0); cy = __shfl(zi[0], lp0); }
        else        { cx = __shfl_xor(zr[SIG[r]], 63); cy = __shfl_xor(zi[SIG[r]], 63); }
        const int k1 = BREV4[r];
        const int k = k2 * 16 + k1;
        const float a = zr[r], b = zi[r];
        const float magA = 0.5f * sqrtf((a + cx) * (a + cx) + (b - cy) * (b - cy));
        const float magB = 0.5f * sqrtf((b + cy) * (b + cy) + (a - cx) * (a - cx));
        if (k <= 512) {
            const int slot = (k & ~15) | (k1 ^ (k2 & 15));  // XOR-swizzle: conflict-free
            smag[w][slot] = make_float2(magA, magB);
        }
    }
    __builtin_amdgcn_sched_barrier(0);

    // ---- sparse mel matmul (triangles) + transposed store ----
    for (int task = lane; task < 2 * N_MELS; task += 64) {
        const int m = task >> 1;
        const int fi = task & 1;
        const unsigned g = (unsigned)(g0 + fi);
        const unsigned bb = g / NUM_FRAMES;
        const unsigned ff = g - bb * NUM_FRAMES;
        const float mlo = MEL_MAX * (float)m / 81.0f;
        const float mhi = MEL_MAX * (float)(m + 2) / 81.0f;
        const int klo = max(1, (int)(mel_to_hz(mlo) / DF) - 1);
        const int khi = min(NSTFT - 2, (int)(mel_to_hz(mhi) / DF) + 2);
        float acc = 0.0f;
        for (int k = klo; k <= khi; ++k) {
            const int slot = (k & ~15) | ((k & 15) ^ ((k >> 4) & 15));
            const float mag = ((const float*)&smag[w][slot])[fi];
            acc = fmaf(mag, fb[k * N_MELS + m], acc);
        }
        out[((size_t)bb * N_MELS + m) * NUM_FRAMES + ff] = acc;
    }
}

extern "C" void kernel_launch(void* const* d_in, const int* in_sizes, int n_in,
                              void* d_out, int out_size, void* d_ws, size_t ws_size,
                              hipStream_t stream) {
    const float* wav    = (const float*)d_in[0];
    const float* window = (const float*)d_in[1];
    const float* fb     = (const float*)d_in[2];
    const float* cosT   = (const float*)d_in[3];
    const float* sinT   = (const float*)d_in[4];
    float* out = (float*)d_out;

    const int blocks = (NPAIRS + 3) / 4;  // 4 waves per block, 1 pair per wave
    melspec_sfft_kernel<<<blocks, 256, 0, stream>>>(wav, window, fb, cosT, sinT, out);
}

// Round 4
// 61.889 us; speedup vs baseline: 15.6845x; 1.4620x over previous
//
#include <hip/hip_runtime.h>
#include <cstddef>

#define HOP 256
#define NSTFT 513
#define N_MELS 80
#define T_AUDIO 320000
#define NUM_FRAMES 1251
#define NBATCH 16
#define TOTAL_FRAMES (NBATCH * NUM_FRAMES)  // 20016 = 1251 blocks * 4 waves * 4 frames

// Slaney mel constants
#define LOGSTEP 0.06875177742094913f
#define MEL_MAX 45.24564047f
#define DF 15.625f

__device__ __forceinline__ float mel_to_hz(float mel) {
    return (mel < 15.0f) ? (200.0f / 3.0f) * mel
                         : 1000.0f * expf(LOGSTEP * (mel - 15.0f));
}

__device__ __forceinline__ int reflect_idx(int j) {
    j = (j < 0) ? -j : j;
    j = (j >= T_AUDIO) ? (2 * T_AUDIO - 2 - j) : j;
    return j;
}

// DPP cross-lane exchange (VALU pipe, replaces ds_bpermute for xor 1/2/8)
#define DPP_XOR1 0xB1   // quad_perm [1,0,3,2]
#define DPP_XOR2 0x4E   // quad_perm [2,3,0,1]
#define DPP_XOR8 0x128  // row_ror:8 (== xor 8 within row of 16)
template<int CTRL>
__device__ __forceinline__ float dppf(float x) {
    return __int_as_float(__builtin_amdgcn_update_dpp(
        0, __float_as_int(x), CTRL, 0xF, 0xF, true));
}

// One cross-lane DIF stage with sign-fma butterfly:
//   lo lanes: q = partner + z (sum), tw = (1,0) -> z = q
//   hi lanes: q = partner - z (diff), z = q * tw
template<class F>
__device__ __forceinline__ void cstage(float (&zr)[2][16], float (&zi)[2][16],
                                       float sg, float twr_, float twi_, F comm) {
    #pragma unroll
    for (int p = 0; p < 2; ++p) {
        #pragma unroll
        for (int r = 0; r < 16; ++r) {
            const float pr  = comm(zr[p][r]);
            const float pim = comm(zi[p][r]);
            const float qr = fmaf(sg, zr[p][r], pr);
            const float qi = fmaf(sg, zi[p][r], pim);
            zr[p][r] = fmaf(qr, twr_, -(qi * twi_));
            zi[p][r] = fmaf(qr, twi_, qi * twr_);
        }
    }
}

// One wave = 4 consecutive global frames (2 real-packed complex FFTs),
// fully independent (no __syncthreads). Four-step 1024 = 16(regs) x 64(lanes):
//   A) 16-pt DIF FFT in registers (constant twiddles)
//   B) cross twiddle W_1024^(lane*k1), built from complex powers of W^lane
//      (one coalesced table read of row n=1, cols 0..63)
//   C) 64-pt DIF FFT across lanes: xor32/16/4 via shfl, xor8/2/1 via DPP
// Then conjugate-symmetry separation -> magnitudes -> swizzled LDS ->
// sparse (triangle-bounded) mel matmul -> transposed store.
__global__ __launch_bounds__(256) void melspec_sfft4_kernel(
    const float* __restrict__ wav,     // 16 x 320000
    const float* __restrict__ window,  // 1024
    const float* __restrict__ fb,      // 513 x 80
    const float* __restrict__ cosT,    // 1024 x 513 (row1 = cos(2pi j/1024))
    const float* __restrict__ sinT,    // 1024 x 513 (row1 = -sin(2pi j/1024))
    float* __restrict__ out)           // 16 x 80 x 1251
{
    __shared__ float2 smag[4][2][NSTFT];  // [wave][pair][slot] ~32.8 KB

    const int lane = threadIdx.x & 63;
    const int w = threadIdx.x >> 6;
    const int g0 = (blockIdx.x * 4 + w) * 4;

    const int BREV4[16] = {0,8,4,12,2,10,6,14,1,9,5,13,3,11,7,15};
    const int SIG[16]   = {0,1,3,2,7,6,5,4,15,14,13,12,11,10,9,8};
    const float W16R[8] = {1.0f, 0.92387953251128674f, 0.70710678118654752f, 0.38268343236508977f,
                           0.0f, -0.38268343236508977f, -0.70710678118654752f, -0.92387953251128674f};
    const float W16I[8] = {0.0f, -0.38268343236508977f, -0.70710678118654752f, -0.92387953251128674f,
                           -1.0f, -0.92387953251128674f, -0.70710678118654752f, -0.38268343236508977f};

    unsigned bf0, ff0, bf3;
    {
        const unsigned g = (unsigned)g0;
        bf0 = g / NUM_FRAMES; ff0 = g - bf0 * NUM_FRAMES;
        bf3 = (unsigned)(g0 + 3) / NUM_FRAMES;
    }

    // ---- window (coalesced, shared by all 4 frames) ----
    float win[16];
    #pragma unroll
    for (int r = 0; r < 16; ++r) win[r] = window[r * 64 + lane];

    // ---- load 4 frames; shared-chunk path exploits 75% overlap ----
    float zr[2][16], zi[2][16];
    if (bf0 == bf3) {
        const float* wb = wav + (size_t)bf0 * T_AUDIO;
        const int base = (int)ff0 * HOP - 512;
        float ch[28];
        #pragma unroll
        for (int c = 0; c < 28; ++c)
            ch[c] = wb[reflect_idx(base + c * 64 + lane)];
        #pragma unroll
        for (int r = 0; r < 16; ++r) {
            zr[0][r] = ch[r]      * win[r];
            zi[0][r] = ch[r + 4]  * win[r];
            zr[1][r] = ch[r + 8]  * win[r];
            zi[1][r] = ch[r + 12] * win[r];
        }
    } else {
        #pragma unroll
        for (int fi = 0; fi < 4; ++fi) {
            const unsigned g = (unsigned)(g0 + fi);
            const unsigned bb = g / NUM_FRAMES;
            const unsigned ffr = g - bb * NUM_FRAMES;
            const float* wb = wav + (size_t)bb * T_AUDIO;
            const int base = (int)ffr * HOP - 512;
            #pragma unroll
            for (int r = 0; r < 16; ++r) {
                const float v = wb[reflect_idx(base + r * 64 + lane)] * win[r];
                if (fi == 0) zr[0][r] = v;
                else if (fi == 1) zi[0][r] = v;
                else if (fi == 2) zr[1][r] = v;
                else zi[1][r] = v;
            }
        }
    }

    const float* twc = cosT + NSTFT;  // row n=1
    const float* tws = sinT + NSTFT;

    // ---- cross twiddles: wk[k] = W_1024^(lane*k), k=0..15 (coalesced base read) ----
    const float w1r = twc[lane];
    const float w1i = tws[lane];
    float wkr[16], wki[16];
    wkr[0] = 1.0f; wki[0] = 0.0f;
    #pragma unroll
    for (int k = 1; k < 16; ++k) {
        wkr[k] = wkr[k-1] * w1r - wki[k-1] * w1i;
        wki[k] = wkr[k-1] * w1i + wki[k-1] * w1r;
    }

    // ---- stage twiddles for phase C (hi lanes only; lo lanes = identity) ----
    float c64[6], s64[6];
    #pragma unroll
    for (int t = 0; t < 6; ++t) {
        const int half = 32 >> t;
        const bool hi = (lane & half) != 0;
        const int jj = (lane & (half - 1)) << (t + 4);
        c64[t] = hi ? twc[jj] : 1.0f;
        s64[t] = hi ? tws[jj] : 0.0f;
    }

    // ---- A) 16-pt DIF FFT in registers, both pairs ----
    #define CBFLY(ar, ai, br, bi, wr, wi) { \
        const float _tr = (ar) - (br), _ti = (ai) - (bi); \
        (ar) += (br); (ai) += (bi); \
        (br) = _tr * (wr) - _ti * (wi); \
        (bi) = _tr * (wi) + _ti * (wr); }

    #pragma unroll
    for (int p = 0; p < 2; ++p) {
        #pragma unroll
        for (int q = 0; q < 8; ++q) CBFLY(zr[p][q], zi[p][q], zr[p][q+8], zi[p][q+8], W16R[q], W16I[q]);
        #pragma unroll
        for (int g = 0; g < 16; g += 8)
            #pragma unroll
            for (int q = 0; q < 4; ++q) CBFLY(zr[p][g+q], zi[p][g+q], zr[p][g+q+4], zi[p][g+q+4], W16R[2*q], W16I[2*q]);
        #pragma unroll
        for (int g = 0; g < 16; g += 4)
            #pragma unroll
            for (int q = 0; q < 2; ++q) CBFLY(zr[p][g+q], zi[p][g+q], zr[p][g+q+2], zi[p][g+q+2], W16R[4*q], W16I[4*q]);
        #pragma unroll
        for (int g = 0; g < 16; g += 2) CBFLY(zr[p][g], zi[p][g], zr[p][g+1], zi[p][g+1], 1.0f, 0.0f);
    }

    // ---- B) cross twiddle ----
    #pragma unroll
    for (int r = 1; r < 16; ++r) {
        const float c1 = wkr[BREV4[r]];
        const float s1 = wki[BREV4[r]];
        #pragma unroll
        for (int p = 0; p < 2; ++p) {
            const float xr = zr[p][r], xi = zi[p][r];
            zr[p][r] = xr * c1 - xi * s1;
            zi[p][r] = xr * s1 + xi * c1;
        }
    }

    // ---- C) 64-pt DIF FFT across lanes ----
    {
        float sg;
        sg = (lane & 32) ? -1.0f : 1.0f;
        cstage(zr, zi, sg, c64[0], s64[0], [](float v) { return __shfl_xor(v, 32); });
        sg = (lane & 16) ? -1.0f : 1.0f;
        cstage(zr, zi, sg, c64[1], s64[1], [](float v) { return __shfl_xor(v, 16); });
        sg = (lane & 8) ? -1.0f : 1.0f;
        cstage(zr, zi, sg, c64[2], s64[2], [](float v) { return dppf<DPP_XOR8>(v); });
        sg = (lane & 4) ? -1.0f : 1.0f;
        cstage(zr, zi, sg, c64[3], s64[3], [](float v) { return __shfl_xor(v, 4); });
        sg = (lane & 2) ? -1.0f : 1.0f;
        cstage(zr, zi, sg, c64[4], s64[4], [](float v) { return dppf<DPP_XOR2>(v); });
        sg = (lane & 1) ? -1.0f : 1.0f;
        cstage(zr, zi, sg, c64[5], s64[5], [](float v) { return dppf<DPP_XOR1>(v); });
    }

    // ---- separation + magnitude + swizzled LDS store ----
    const int k2 = (int)(__brev((unsigned)lane) >> 26);
    const int lp0 = (int)(__brev((unsigned)((64 - k2) & 63)) >> 26);
    #pragma unroll
    for (int p = 0; p < 2; ++p) {
        #pragma unroll
        for (int r = 0; r < 16; ++r) {
            float cx, cy;
            if (r == 0) { cx = __shfl(zr[p][0], lp0); cy = __shfl(zi[p][0], lp0); }
            else        { cx = __shfl_xor(zr[p][SIG[r]], 63); cy = __shfl_xor(zi[p][SIG[r]], 63); }
            const int k1 = BREV4[r];
            const int k = k2 * 16 + k1;
            const float a = zr[p][r], b = zi[p][r];
            const float magA = 0.5f * sqrtf((a + cx) * (a + cx) + (b - cy) * (b - cy));
            const float magB = 0.5f * sqrtf((b + cy) * (b + cy) + (a - cx) * (a - cx));
            if (k <= 512) {
                const int slot = (k & ~15) | (k1 ^ (k2 & 15));
                smag[w][p][slot] = make_float2(magA, magB);
            }
        }
    }

    // ---- sparse mel matmul (5 tasks/lane exactly: 80 mels x 4 frames) ----
    #pragma unroll
    for (int i = 0; i < 5; ++i) {
        const int task = lane + 64 * i;   // < 320
        const int m = task >> 2;
        const int fi = task & 3;
        const unsigned g = (unsigned)(g0 + fi);
        const unsigned bb = g / NUM_FRAMES;
        const unsigned ffr = g - bb * NUM_FRAMES;
        const float mlo = MEL_MAX * (float)m / 81.0f;
        const float mhi = MEL_MAX * (float)(m + 2) / 81.0f;
        const int klo = max(1, (int)(mel_to_hz(mlo) / DF) - 1);
        const int khi = min(NSTFT - 2, (int)(mel_to_hz(mhi) / DF) + 2);
        float acc = 0.0f;
        for (int k = klo; k <= khi; ++k) {
            const int slot = (k & ~15) | ((k & 15) ^ ((k >> 4) & 15));
            const float2 v = smag[w][fi >> 1][slot];
            const float mag = (fi & 1) ? v.y : v.x;
            acc = fmaf(mag, fb[k * N_MELS + m], acc);
        }
        out[((size_t)bb * N_MELS + m) * NUM_FRAMES + ffr] = acc;
    }
}

extern "C" void kernel_launch(void* const* d_in, const int* in_sizes, int n_in,
                              void* d_out, int out_size, void* d_ws, size_t ws_size,
                              hipStream_t stream) {
    const float* wav    = (const float*)d_in[0];
    const float* window = (const float*)d_in[1];
    const float* fb     = (const float*)d_in[2];
    const float* cosT   = (const float*)d_in[3];
    const float* sinT   = (const float*)d_in[4];
    float* out = (float*)d_out;

    const int blocks = TOTAL_FRAMES / 16;  // 1251: 4 waves/block, 4 frames/wave
    melspec_sfft4_kernel<<<blocks, 256, 0, stream>>>(wav, window, fb, cosT, sinT, out);
}